// Round 1
// baseline (125.144 us; speedup 1.0000x reference)
//
#include <hip/hip_runtime.h>

// LengthRegulator: B=16, T=512, D=384, MAX_LEN=4096
// out[b,f,:] = x[b, searchsorted_right(cum[b], f).clip(0,T-1), :] * (f < min(mel_len,max_len))
// mel_len[b] = sum(durations[b])

#define B_ 16
#define T_ 512
#define D_ 384
#define MAXLEN_ 4096
#define ROWV4_ (D_ / 4)                 // 96 float4 per row
#define OUT_ELEMS_ (B_ * MAXLEN_ * D_) // 25,165,824

// Kernel 1: per-batch cumsum + frame->token scatter map + mel_len write.
__global__ __launch_bounds__(T_) void lr_scan_kernel(const int* __restrict__ dur,
                                                     const int* __restrict__ max_len_p,
                                                     int* __restrict__ ws_idx,
                                                     float* __restrict__ mel_out) {
    __shared__ int s[T_];
    const int b = blockIdx.x;
    const int t = threadIdx.x;
    const int max_len = max_len_p[0];

    const int d = dur[b * T_ + t];
    s[t] = d;
    __syncthreads();

    // Hillis-Steele inclusive scan over 512 elements (9 steps)
    #pragma unroll
    for (int off = 1; off < T_; off <<= 1) {
        const int add = (t >= off) ? s[t - off] : 0;
        __syncthreads();
        s[t] += add;
        __syncthreads();
    }
    const int cum = s[t];      // inclusive cumsum
    const int start = cum - d; // exclusive cumsum
    const int mel = s[T_ - 1];

    // init this batch's frame map to -1 (masked), then scatter token ids
    int* wb = ws_idx + b * MAXLEN_;
    for (int j = t; j < MAXLEN_; j += T_) wb[j] = -1;
    __syncthreads(); // orders the global init before the scatter (vmcnt(0)+barrier)

    for (int j = 0; j < d; ++j) {
        const int f = start + j;
        if (f < max_len && f < MAXLEN_) wb[f] = t;
    }

    if (t == 0) mel_out[b] = (float)mel;
}

// Kernel 2: gather rows per the frame map; float4-vectorized, fully coalesced.
__global__ __launch_bounds__(256) void lr_gather_kernel(const float4* __restrict__ x,
                                                        const int* __restrict__ ws_idx,
                                                        float4* __restrict__ out) {
    const int g = blockIdx.x * 256 + threadIdx.x; // one float4 per thread
    const int row = g / ROWV4_;                   // (b*MAXLEN + f)
    const int col = g - row * ROWV4_;
    const int idx = ws_idx[row];
    float4 v;
    if (idx >= 0) {
        const int b = row >> 12; // row / MAXLEN_
        v = x[(b * T_ + idx) * ROWV4_ + col];
    } else {
        v = make_float4(0.f, 0.f, 0.f, 0.f);
    }
    out[g] = v;
}

extern "C" void kernel_launch(void* const* d_in, const int* in_sizes, int n_in,
                              void* d_out, int out_size, void* d_ws, size_t ws_size,
                              hipStream_t stream) {
    const float* x = (const float*)d_in[0];
    const int* dur = (const int*)d_in[1];
    const int* max_len_p = (const int*)d_in[2]; // device scalar — read in-kernel only

    float* out = (float*)d_out;
    float* mel_out = out + OUT_ELEMS_; // mel_len written as f32 at the tail
    int* ws_idx = (int*)d_ws;          // B*MAXLEN ints = 256 KB of scratch

    lr_scan_kernel<<<B_, T_, 0, stream>>>(dur, max_len_p, ws_idx, mel_out);

    const int total_v4 = OUT_ELEMS_ / 4; // 6,291,456
    lr_gather_kernel<<<total_v4 / 256, 256, 0, stream>>>(
        (const float4*)x, ws_idx, (float4*)out);
}

// Round 2
// 121.686 us; speedup vs baseline: 1.0284x; 1.0284x over previous
//
#include <hip/hip_runtime.h>

// LengthRegulator: B=16, T=512, D=384, MAX_LEN=4096
// out[b,f,:] = x[b, searchsorted_right(cum[b], f).clip(0,T-1), :] * (f < min(mel,max_len))
// mel_len[b] = sum(durations[b])  (written as f32 at the tail of d_out)

#define B_ 16
#define T_ 512
#define D_ 384
#define MAXLEN_ 4096
#define ROWV4_ (D_ / 4)                 // 96 float4 per row
#define OUT_ELEMS_ (B_ * MAXLEN_ * D_) // 25,165,824
#define BLOCKS_PER_BATCH_ ((MAXLEN_ * ROWV4_) / 256) // 1536 — block never spans batches

// Kernel 1: per-batch inclusive cumsum -> ws (B*T ints); mel_len -> d_out tail.
// Shuffle-based scan: 6 shfl steps per wave + 8-wide wave-sum scan, 2 barriers.
__global__ __launch_bounds__(T_) void lr_scan_kernel(const int* __restrict__ dur,
                                                     int* __restrict__ cum_ws,
                                                     float* __restrict__ mel_out) {
    const int b = blockIdx.x, t = threadIdx.x;
    const int lane = t & 63, w = t >> 6;
    int v = dur[b * T_ + t];
    #pragma unroll
    for (int off = 1; off < 64; off <<= 1) {
        int n = __shfl_up(v, off);
        if (lane >= off) v += n;
    }
    __shared__ int wsum[8];
    if (lane == 63) wsum[w] = v;
    __syncthreads();
    if (t < 8) { // scan the 8 wave totals (lanes 0..7 of wave 0, reads only lower active lanes)
        int u = wsum[t];
        #pragma unroll
        for (int off = 1; off < 8; off <<= 1) {
            int n = __shfl_up(u, off);
            if (t >= off) u += n;
        }
        wsum[t] = u;
    }
    __syncthreads();
    const int cum = v + (w > 0 ? wsum[w - 1] : 0);
    cum_ws[b * T_ + t] = cum;
    if (t == T_ - 1) mel_out[b] = (float)cum;
}

// Kernel 2: per-block LDS copy of this batch's cum, branchless binary search
// per output row, float4 gather + coalesced write.
__global__ __launch_bounds__(256) void lr_gather_kernel(const float4* __restrict__ x,
                                                        const int* __restrict__ cum_ws,
                                                        const int* __restrict__ max_len_p,
                                                        float4* __restrict__ out) {
    __shared__ int s[T_];
    const int t = threadIdx.x;
    const int b = blockIdx.x / BLOCKS_PER_BATCH_;
    const int* cb = cum_ws + b * T_;
    s[t] = cb[t];
    s[t + 256] = cb[t + 256];
    __syncthreads();

    const int g = blockIdx.x * 256 + t;   // one float4 per thread
    const int row = g / ROWV4_;           // global row = b*MAXLEN + f
    const int col = g - row * ROWV4_;
    const int f = row & (MAXLEN_ - 1);
    const int mel = s[T_ - 1];
    const int max_len = max_len_p[0];

    float4 v = make_float4(0.f, 0.f, 0.f, 0.f);
    if (f < mel && f < max_len) {
        // searchsorted(cum, f, 'right') = #{i : cum[i] <= f}; 9-step branchless
        int idx = 0;
        #pragma unroll
        for (int step = 256; step > 0; step >>= 1)
            if (s[idx + step - 1] <= f) idx += step;
        if (idx > T_ - 1) idx = T_ - 1; // clip (unreachable given f < mel, kept for safety)
        v = x[(b * T_ + idx) * ROWV4_ + col];
    }
    out[g] = v;
}

extern "C" void kernel_launch(void* const* d_in, const int* in_sizes, int n_in,
                              void* d_out, int out_size, void* d_ws, size_t ws_size,
                              hipStream_t stream) {
    const float* x = (const float*)d_in[0];
    const int* dur = (const int*)d_in[1];
    const int* max_len_p = (const int*)d_in[2]; // device scalar — read in-kernel only

    float* out = (float*)d_out;
    float* mel_out = out + OUT_ELEMS_;
    int* cum_ws = (int*)d_ws; // B*T ints = 32 KB scratch

    lr_scan_kernel<<<B_, T_, 0, stream>>>(dur, cum_ws, mel_out);

    const int total_v4 = OUT_ELEMS_ / 4; // 6,291,456
    lr_gather_kernel<<<total_v4 / 256, 256, 0, stream>>>(
        (const float4*)x, cum_ws, max_len_p, (float4*)out);
}